// Round 1
// baseline (1614.151 us; speedup 1.0000x reference)
//
#include <hip/hip_runtime.h>

// SNN layer, round 9: exact-enough Ozaki int8 GEMM replaces fp64 MFMA.
//
//  currents[t,b,o] = sum_i x[b,i,t]*w[i,o]. Spike decisions tolerate
//  |dcur| ~3e-5 abs (42 product bits) -- fp64 (prev: 1126us @ 76% of the
//  78.6TF f64-MFMA ceiling) is ~4000x overkill. Scheme:
//    x = SA(b,t) * sum_s a_s 128^-(s+1), w = SB(o) * sum_s b_s 128^-(s+1)
//    (6 signed 7-bit slices, exact trunc split in fp32)
//    cur = SA*SB * sum_{c=0..5} 128^-(c+2) * [ sum_k sum_{i+j=c} a_i b_j ]
//  Inner sums exact in i32 via v_mfma_i32_32x32x32_i8 (4404 TOPS ubench).
//  21 slice-pair passes but only 6 accumulators (grouped by weight c).
//  Slice residual window 2^-42 -> cur err rms ~4e-6 -> E[flipped spikes]~3e-4.
//  k-slot layout errors cancel (A/B use identical (lane,byte)->k map);
//  D reg->row mapping probed at runtime (same trick as the f64 kernel).
//
//  Scan kernel: unchanged (proven, NC=32 double-buffer).
//
//  ws: vstate 256KB | SB 8KB | wp 6MB | SA 32*tca*4 | xp 6*32*tca*1024 | cur tca*256KB
//  tca=512 -> 241.5MB total (ws proven >= 262MB by previous rounds).

#define NB 32
#define NI 1024
#define NO 1024
#define NT 1000
#define NS 6          // slices per operand (7 bits each)
#define BT 64         // t rows per block tile
#define BO 64         // o cols per block tile
#define KI 64         // k per LDS stage
#define ROWB (NS*64)  // 384 B per LDS row: 6 slice-chunks x 64 k-bytes, XOR-swizzled

typedef int i32x4  __attribute__((ext_vector_type(4)));
typedef int i32x16 __attribute__((ext_vector_type(16)));

// ---- per-o column scale of w: SB = 2^(e+1) > colmax, plus 1/SB ----
__global__ void snn_wscale(const float* __restrict__ w, float* __restrict__ sb)
{
    const int o = blockIdx.x * 256 + threadIdx.x;
    float m = 0.f;
    for (int i = 0; i < NI; ++i) m = fmaxf(m, fabsf(w[(size_t)i * NO + o]));
    const unsigned bits = __float_as_uint(m);
    const int e = (bits >> 23) & 255;
    float S = 0.f, Si = 0.f;
    if (e) {
        S  = __uint_as_float((unsigned)(e + 1) << 23);
        Si = __uint_as_float((unsigned)(253 - e) << 23);
    }
    sb[o] = S;
    sb[NO + o] = Si;
}

// ---- slice w into 6 int8 planes wp[s][o][i] (i contiguous; LDS transpose) ----
__global__ void snn_wslice(const float* __restrict__ w, const float* __restrict__ sb,
                           signed char* __restrict__ wp)
{
    __shared__ int sldw[NS][64][16];   // 24KB, dword cols XOR-swizzled by row
    __shared__ float sinv[64];
    const int tid = threadIdx.x;
    const int o0 = blockIdx.x * 64;
    const int ol = tid & 63, iq = tid >> 6;
    if (tid < 64) sinv[tid] = sb[NO + o0 + tid];
    __syncthreads();
    const float inv = sinv[ol];
    for (int ic = 0; ic < NI; ic += 64) {
        for (int q4 = 0; q4 < 16; q4 += 4) {
            int pk[NS] = {0, 0, 0, 0, 0, 0};
#pragma unroll
            for (int j = 0; j < 4; ++j) {
                const int i = ic + iq * 16 + q4 + j;
                float wv = w[(size_t)i * NO + o0 + ol] * inv;   // exact (pow2 scale)
#pragma unroll
                for (int s = 0; s < NS; ++s) {
                    const float f = wv * 128.f;     // exact, |f|<128
                    const int a = (int)f;           // trunc, in [-127,127]
                    wv = f - (float)a;              // exact fractional part
                    pk[s] |= (a & 255) << (8 * j);
                }
            }
            const int cdw = (iq * 16 + q4) >> 2;
#pragma unroll
            for (int s = 0; s < NS; ++s)
                sldw[s][ol][cdw ^ (ol & 15)] = pk[s];
        }
        __syncthreads();
        for (int p = 0; p < 24; ++p) {
            const int idx = p * 256 + tid;
            const int iw = idx & 15, r = (idx >> 4) & 63, s = idx >> 10;
            *(int*)&wp[((size_t)s * NO + o0 + r) * NI + ic + iw * 4] =
                sldw[s][r][iw ^ (r & 15)];
        }
        __syncthreads();
    }
}

// ---- per-(b,t) scale + slice x into xp[s][b][tlocal][i] (i contiguous) ----
__global__ void snn_xprep(const float* __restrict__ x, signed char* __restrict__ xp,
                          float* __restrict__ sa, int t0, int tca)
{
    __shared__ int sldw[NS][64][16];
    __shared__ float red[4][64];
    __shared__ float sinv[64];
    const int tid = threadIdx.x;
    const int b = blockIdx.y;
    const int tt = blockIdx.x * 64;
    const int tl = tid & 63, iq = tid >> 6;
    const int tg = t0 + tt + tl;
    const bool valid = (tg < NT);
    const float* xb = x + (size_t)b * NI * NT;

    // phase 1: rowmax over i (coalesced over t)
    float m = 0.f;
    if (valid)
        for (int i = iq; i < NI; i += 4) m = fmaxf(m, fabsf(xb[(size_t)i * NT + tg]));
    red[iq][tl] = m;
    __syncthreads();
    if (iq == 0) {
        m = fmaxf(fmaxf(red[0][tl], red[1][tl]), fmaxf(red[2][tl], red[3][tl]));
        const unsigned bits = __float_as_uint(m);
        const int e = (bits >> 23) & 255;
        float S = 0.f, Si = 0.f;
        if (e) {
            S  = __uint_as_float((unsigned)(e + 1) << 23);
            Si = __uint_as_float((unsigned)(253 - e) << 23);
        }
        sa[(size_t)b * tca + tt + tl] = S;
        sinv[tl] = Si;
    }
    __syncthreads();
    const float inv = sinv[tl];

    // phase 2: slice + LDS transpose (reads L2-hot), write [t][i] rows
    for (int ic = 0; ic < NI; ic += 64) {
        for (int q4 = 0; q4 < 16; q4 += 4) {
            int pk[NS] = {0, 0, 0, 0, 0, 0};
#pragma unroll
            for (int j = 0; j < 4; ++j) {
                const int i = ic + iq * 16 + q4 + j;
                float wv = valid ? xb[(size_t)i * NT + tg] * inv : 0.f;
#pragma unroll
                for (int s = 0; s < NS; ++s) {
                    const float f = wv * 128.f;
                    const int a = (int)f;
                    wv = f - (float)a;
                    pk[s] |= (a & 255) << (8 * j);
                }
            }
            const int cdw = (iq * 16 + q4) >> 2;
#pragma unroll
            for (int s = 0; s < NS; ++s)
                sldw[s][tl][cdw ^ (tl & 15)] = pk[s];
        }
        __syncthreads();
        for (int p = 0; p < 24; ++p) {
            const int idx = p * 256 + tid;
            const int iw = idx & 15, r = (idx >> 4) & 63, s = idx >> 10;
            *(int*)&xp[(((size_t)s * NB + b) * tca + tt + r) * NI + ic + iw * 4] =
                sldw[s][r][iw ^ (r & 15)];
        }
        __syncthreads();
    }
}

// ---- int8 MFMA GEMM: block 64t x 64o, 4 waves of 32x32, 6 weight-grouped accs ----
__global__ __launch_bounds__(256, 2)
void snn_gemm_i8(const signed char* __restrict__ xp, const signed char* __restrict__ wp,
                 const float* __restrict__ sa, const float* __restrict__ sb,
                 double* __restrict__ cur, int t0, int tca)
{
    __shared__ signed char As[BT * ROWB];   // 24KB: row t x (6 slices x 64 k)
    __shared__ signed char Bs[BO * ROWB];   // 24KB: row o x (6 slices x 64 k)

    const int tid  = threadIdx.x;
    const int lane = tid & 63;
    const int wave = tid >> 6;
    const int wm = (wave >> 1) * 32;   // t offset of wave tile
    const int wn = (wave & 1) * 32;    // o offset
    const int l31 = lane & 31;
    const int hi  = lane >> 5;

    const int o0 = blockIdx.x * BO;
    const int bt = blockIdx.y * BT;
    const int b  = blockIdx.z;

    // Probe D reg->row (col is lane&31): A=I(32x32), B[k][n]=k => D[m][n]=m.
    int prow[16];
    {
        i32x4 pa, pb;
#pragma unroll
        for (int q = 0; q < 4; ++q) {
            int va = 0, vb = 0;
#pragma unroll
            for (int jj = 0; jj < 4; ++jj) {
                const int k = 16 * hi + q * 4 + jj;
                if (l31 == k) va |= 1 << (8 * jj);
                vb |= (k & 255) << (8 * jj);
            }
            pa[q] = va; pb[q] = vb;
        }
        i32x16 pp = (i32x16)0;
        pp = __builtin_amdgcn_mfma_i32_32x32x32_i8(pa, pb, pp, 0, 0, 0);
#pragma unroll
        for (int r = 0; r < 16; ++r) prow[r] = pp[r] & 31;
    }

    i32x16 acc[NS];
#pragma unroll
    for (int c = 0; c < NS; ++c) acc[c] = (i32x16)0;

    const size_t xps = (size_t)NB * tca * NI;   // plane stride of xp
    const size_t wps = (size_t)NO * NI;         // plane stride of wp
    const signed char* xpb = xp + ((size_t)b * tca + bt) * NI;
    const signed char* wpb = wp + (size_t)o0 * NI;

    const int sr  = tid >> 2;            // staging row 0..63
    const int sk  = (tid & 3) * 16;      // staging k-byte 0/16/32/48
    const int ssw = (sr & 7) << 4;       // LDS XOR swizzle (store side)
    const int ra  = wm + l31;            // A frag row
    const int rb  = wn + l31;            // B frag row
    const int asw = (ra & 7) << 4;       // LDS XOR swizzle (read side)
    const int bsw = (rb & 7) << 4;

    for (int kb = 0; kb < NI; kb += KI) {
        __syncthreads();
        i32x4 ta[NS], tb[NS];
#pragma unroll
        for (int s = 0; s < NS; ++s) {
            ta[s] = *(const i32x4*)&xpb[s * xps + (size_t)sr * NI + kb + sk];
            tb[s] = *(const i32x4*)&wpb[s * wps + (size_t)sr * NI + kb + sk];
        }
#pragma unroll
        for (int s = 0; s < NS; ++s) {
            const int d = sr * ROWB + ((s * 64 + sk) ^ ssw);
            *(i32x4*)&As[d] = ta[s];
            *(i32x4*)&Bs[d] = tb[s];
        }
        __syncthreads();
#pragma unroll
        for (int ks = 0; ks < 2; ++ks) {
            i32x4 af[NS], bf[NS];
#pragma unroll
            for (int s = 0; s < NS; ++s) {
                const int off = s * 64 + ks * 32 + 16 * hi;
                af[s] = *(const i32x4*)&As[ra * ROWB + (off ^ asw)];
                bf[s] = *(const i32x4*)&Bs[rb * ROWB + (off ^ bsw)];
            }
            // 21 slice pairs grouped by weight c=i+j (descending c: spreads
            // same-acc MFMAs for dependency slack)
#pragma unroll
            for (int i = 0; i < NS; ++i)
#pragma unroll
                for (int c = NS - 1; c >= i; --c)
                    acc[c] = __builtin_amdgcn_mfma_i32_32x32x32_i8(
                        af[i], bf[c - i], acc[c], 0, 0, 0);
        }
    }

    // epilogue: exact i32 partials -> fp64 currents
    const double c128[NS] = {0x1p-14, 0x1p-21, 0x1p-28, 0x1p-35, 0x1p-42, 0x1p-49};
    const int ocol = o0 + wn + l31;
    const double sbv = (double)sb[ocol];
#pragma unroll
    for (int r = 0; r < 16; ++r) {
        const int trow = bt + wm + prow[r];
        double v = 0.0;
#pragma unroll
        for (int c = 0; c < NS; ++c) v += (double)acc[c][r] * c128[c];
        v *= (double)sa[(size_t)b * tca + trow] * sbv;
        if (t0 + trow < NT)
            cur[((size_t)trow * NB + b) * NO + ocol] = v;
    }
}

// LIF scan: one thread per (b,o); cur chunk is [tc][b*NO+o] fp64. 32-step
// double buffer; 128B contiguous stores per thread per iter. (Unchanged, proven.)
#define NC 32
__global__ __launch_bounds__(64)
void snn_scan_f64(const double* __restrict__ cur, float* __restrict__ out,
                  double* __restrict__ vstate, int t0, int len)
{
    const int gid = blockIdx.x * 64 + threadIdx.x;   // b*NO + o
    const double dt = 0.001 / 50.0;                  // MS / TAU, IEEE double

    double v = (t0 == 0) ? 0.0 : vstate[gid];
    const double* cp = cur + gid;                    // stride NB*NO per t-step
    float* op = out + (size_t)gid * NT + t0;         // thread-contiguous in t

    const size_t ts = (size_t)NB * NO;               // 32768
    const int nb = len / NC;                         // full 32-blocks
    const int rem = len - nb * NC;                   // tail (multiple of 8)

    double A[NC], B[NC];
#pragma unroll
    for (int j = 0; j < NC; ++j) A[j] = (j < len) ? cp[(size_t)j * ts] : 0.0;

    for (int blk = 0; blk < nb; ++blk) {
        const int next = (blk + 1) * NC;
#pragma unroll
        for (int j = 0; j < NC; ++j)
            B[j] = (next + j < len) ? cp[(size_t)(next + j) * ts] : 0.0;

#pragma unroll
        for (int q = 0; q < NC; q += 8) {
            float s[8];
#pragma unroll
            for (int j = 0; j < 8; ++j) {
                v = v + (A[q + j] - v) * dt;
                const bool sp = (v >= 1.0);
                s[j] = sp ? 1.0f : 0.0f;
                if (sp) v = 0.0;
            }
            *(float4*)(op + q)     = make_float4(s[0], s[1], s[2], s[3]);
            *(float4*)(op + q + 4) = make_float4(s[4], s[5], s[6], s[7]);
        }
        op += NC;
#pragma unroll
        for (int j = 0; j < NC; ++j) A[j] = B[j];
    }

    for (int q = 0; q < rem; q += 8) {               // tail (data already in A)
        float s[8];
#pragma unroll
        for (int j = 0; j < 8; ++j) {
            v = v + (A[q + j] - v) * dt;
            const bool sp = (v >= 1.0);
            s[j] = sp ? 1.0f : 0.0f;
            if (sp) v = 0.0;
        }
        *(float4*)(op + q)     = make_float4(s[0], s[1], s[2], s[3]);
        *(float4*)(op + q + 4) = make_float4(s[4], s[5], s[6], s[7]);
    }
    vstate[gid] = v;
}

extern "C" void kernel_launch(void* const* d_in, const int* in_sizes, int n_in,
                              void* d_out, int out_size, void* d_ws, size_t ws_size,
                              hipStream_t stream)
{
    const float* x = (const float*)d_in[0];
    const float* w = (const float*)d_in[1];
    float* out = (float*)d_out;

    char* p = (char*)d_ws;
    double* vstate = (double*)p;         p += (size_t)NB * NO * 8;     // 256KB
    float* sbv = (float*)p;              p += (size_t)2 * NO * 4;      // 8KB
    signed char* wp = (signed char*)p;   p += (size_t)NS * NO * NI;    // 6MB

    const size_t fixed = (size_t)(p - (char*)d_ws);
    const size_t per_t = (size_t)NB * 4                // SA
                       + (size_t)NS * NB * NI          // x slices
                       + (size_t)NB * NO * 8;          // cur
    int tca = 512;                                     // t-chunk (mult of 64)
    while (tca > 64 && fixed + (size_t)tca * per_t > ws_size) tca -= 64;

    float* sa = (float*)p;               p += (size_t)NB * tca * 4;
    signed char* xpl = (signed char*)p;  p += (size_t)NS * NB * tca * NI;
    double* cur = (double*)p;

    snn_wscale<<<dim3(NO / 256), dim3(256), 0, stream>>>(w, sbv);
    snn_wslice<<<dim3(NO / 64), dim3(256), 0, stream>>>(w, sbv, wp);

    for (int t0 = 0; t0 < NT; t0 += tca) {
        const int len = (NT - t0 < tca) ? (NT - t0) : tca;
        const int tiles = (len + BT - 1) / BT;
        snn_xprep<<<dim3(tiles, NB), dim3(256), 0, stream>>>(x, xpl, sa, t0, tca);
        snn_gemm_i8<<<dim3(NO / BO, tiles, NB), dim3(256), 0, stream>>>(
            xpl, wp, sa, sbv, cur, t0, tca);
        snn_scan_f64<<<dim3((NB * NO) / 64), dim3(64), 0, stream>>>(
            cur, out, vstate, t0, len);
    }
}

// Round 3
// 1289.173 us; speedup vs baseline: 1.2521x; 1.2521x over previous
//
#include <hip/hip_runtime.h>

// SNN layer, round 10b: pipelined int8 Ozaki GEMM (exact numerics proven in r9).
// RESUBMISSION of round 10 — that bench died with "container failed twice"
// (infra; round 1 already showed a 421s npz push). Kernel re-audited for
// deadlock / buffer races / OOB page faults: none found. Source unchanged.
//
//  r9 result: absmax 0.0 (int8 slice scheme decision-exact), but GEMM at
//  MfmaUtil 41% (m97-structure ceiling: single-buffer LDS + vmcnt(0) drains)
//  and 5e7 LDS bank-conflict cycles (~20%/dispatch). Prepasses underparallel.
//
//  This round (T1+T2-by-construction+T3+T4):
//   - xp/wp stored pre-tiled as the GEMM's exact LDS image:
//       [kb][s][kc(16k)][row(64)][16B]  (12 KB per kb per matrix tile)
//     -> staging is pure global_load_lds width=16 (no ds_write, no VGPR trip)
//     -> fragment ds_read_b128: 32 lanes read 512B contiguous = 0 bank conflicts
//   - K-loop: KI=32, TRIPLE-buffered LDS (72 KB), counted s_waitcnt vmcnt(12)
//     (never 0 in loop) + raw s_barrier pairs; ds_reads forced complete via
//     lgkmcnt(0)+sched_barrier before the tail barrier (race rule, m152/r282).
//   - bijective XCD swizzle on flattened block id (nwg divisible by 8).
//   - wslice 16->256 blocks; xprep split into xscale + 4x-parallel xslice with
//     fully-coalesced tiled writes (1KB contiguous per wave instruction).
//  Scan kernel unchanged (proven).
//
//  ws: vstate 256KB | SB 8KB | wp 6MB | SA | xp (tiled) | cur   (tca=512: 230MB)

#define NB 32
#define NI 1024
#define NO 1024
#define NT 1000
#define NS 6          // slices per operand (7 bits each, base 128)
#define BT 64         // t rows per block tile
#define BO 64         // o cols per block tile
#define KI 32         // k per pipeline stage
#define NKB (NI/KI)   // 32 k-blocks
#define TILEB (NS*2*64*16)   // 12288 B per (kb, matrix): [s][kc][row][16]

typedef int i32x4  __attribute__((ext_vector_type(4)));
typedef int i32x16 __attribute__((ext_vector_type(16)));

typedef const __attribute__((address_space(1))) void GVOID;
typedef __attribute__((address_space(3))) void LVOID;
#define GLDS16(g, l) __builtin_amdgcn_global_load_lds((GVOID*)(g), (LVOID*)(l), 16, 0, 0)

// ---- per-o column scale of w: SB = 2^(e+1) > colmax, plus 1/SB ----
__global__ void snn_wscale(const float* __restrict__ w, float* __restrict__ sb)
{
    __shared__ float red[4][64];
    const int tid = threadIdx.x;
    const int ol = tid & 63, iq = tid >> 6;
    const int o = blockIdx.x * 64 + ol;
    float m = 0.f;
    for (int i = iq; i < NI; i += 4) m = fmaxf(m, fabsf(w[(size_t)i * NO + o]));
    red[iq][ol] = m;
    __syncthreads();
    if (iq == 0) {
        m = fmaxf(fmaxf(red[0][ol], red[1][ol]), fmaxf(red[2][ol], red[3][ol]));
        const int e = (__float_as_uint(m) >> 23) & 255;
        float S = 0.f, Si = 0.f;
        if (e) {
            S  = __uint_as_float((unsigned)(e + 1) << 23);
            Si = __uint_as_float((unsigned)(253 - e) << 23);
        }
        sb[o] = S;
        sb[NO + o] = Si;
    }
}

// ---- slice w into tiled planes wp[otile][kb][s][kc][o][16] ----
__global__ void snn_wslice(const float* __restrict__ w, const float* __restrict__ sb,
                           signed char* __restrict__ wp)
{
    __shared__ int sldw[NS][64][16];   // XOR-swizzled dword cols (2-way max)
    const int tid = threadIdx.x;
    const int ol = tid & 63, iq = tid >> 6;
    const int o0 = blockIdx.x * 64, ic = blockIdx.y * 64;
    const float inv = sb[NO + o0 + ol];
#pragma unroll
    for (int q4 = 0; q4 < 16; q4 += 4) {
        int pk[NS] = {0, 0, 0, 0, 0, 0};
#pragma unroll
        for (int j = 0; j < 4; ++j) {
            const int i = ic + iq * 16 + q4 + j;
            float wv = w[(size_t)i * NO + o0 + ol] * inv;   // exact (pow2 scale)
#pragma unroll
            for (int s = 0; s < NS; ++s) {
                const float f = wv * 128.f;     // exact, |f|<128
                const int a = (int)f;           // trunc in [-127,127]
                wv = f - (float)a;              // exact remainder
                pk[s] |= (a & 255) << (8 * j);
            }
        }
        const int cdw = (iq * 16 + q4) >> 2;
#pragma unroll
        for (int s = 0; s < NS; ++s) sldw[s][ol][cdw ^ (ol & 15)] = pk[s];
    }
    __syncthreads();
    signed char* tb = wp + (size_t)blockIdx.x * (NKB * TILEB) + (size_t)(ic >> 5) * TILEB;
#pragma unroll
    for (int p = 0; p < 24; ++p) {       // 6144 dwords, contiguous per kb-half
        const int idx = p * 256 + tid;
        const int kbi = idx >= 3072;
        const int ld  = idx - (kbi ? 3072 : 0);
        const int s  = ld >> 9;
        const int kc = (ld >> 8) & 1;
        const int r  = (ld >> 2) & 63;
        const int d4 = ld & 3;
        *(int*)&tb[(size_t)kbi * TILEB + (size_t)ld * 4] =
            sldw[s][r][(kbi * 8 + kc * 4 + d4) ^ (r & 15)];
    }
}

// ---- per-(b,t) scale SA = 2^(e+1) > rowmax ----
__global__ void snn_xscale(const float* __restrict__ x, float* __restrict__ sa,
                           int t0, int tca)
{
    __shared__ float red[4][64];
    const int tid = threadIdx.x;
    const int tl = tid & 63, iq = tid >> 6;
    const int b = blockIdx.y;
    const int tt = blockIdx.x * 64;
    const int tg = t0 + tt + tl;
    const float* xb = x + (size_t)b * NI * NT;
    float m = 0.f;
    if (tg < NT)
        for (int i = iq; i < NI; i += 4) m = fmaxf(m, fabsf(xb[(size_t)i * NT + tg]));
    red[iq][tl] = m;
    __syncthreads();
    if (iq == 0) {
        m = fmaxf(fmaxf(red[0][tl], red[1][tl]), fmaxf(red[2][tl], red[3][tl]));
        const int e = (__float_as_uint(m) >> 23) & 255;
        sa[(size_t)b * tca + tt + tl] = e ? __uint_as_float((unsigned)(e + 1) << 23) : 0.f;
    }
}

// ---- slice x into tiled planes xp[b][tile][kb][s][kc][t][16] ----
__global__ void snn_xslice(const float* __restrict__ x, const float* __restrict__ sa,
                           signed char* __restrict__ xp, int t0, int tca, int ntiles)
{
    __shared__ int sldw[NS][64][16];
    const int tid = threadIdx.x;
    const int tl = tid & 63, iq = tid >> 6;
    const int b = blockIdx.y;
    const int tile = blockIdx.x;
    const int tg = t0 + tile * 64 + tl;
    const bool valid = (tg < NT);
    const float* xb = x + (size_t)b * NI * NT;
    const float S = sa[(size_t)b * tca + tile * 64 + tl];
    const float inv = (S > 0.f)
        ? __uint_as_float((254u - (__float_as_uint(S) >> 23)) << 23) : 0.f;  // exact 1/S
    signed char* tb = xp + (size_t)(b * ntiles + tile) * (NKB * TILEB);

    for (int c4 = 0; c4 < 4; ++c4) {
        const int ic = blockIdx.z * 256 + c4 * 64;
#pragma unroll
        for (int q4 = 0; q4 < 16; q4 += 4) {
            int pk[NS] = {0, 0, 0, 0, 0, 0};
#pragma unroll
            for (int j = 0; j < 4; ++j) {
                const int i = ic + iq * 16 + q4 + j;
                float wv = valid ? xb[(size_t)i * NT + tg] * inv : 0.f;
#pragma unroll
                for (int s = 0; s < NS; ++s) {
                    const float f = wv * 128.f;
                    const int a = (int)f;
                    wv = f - (float)a;
                    pk[s] |= (a & 255) << (8 * j);
                }
            }
            const int cdw = (iq * 16 + q4) >> 2;
#pragma unroll
            for (int s = 0; s < NS; ++s) sldw[s][tl][cdw ^ (tl & 15)] = pk[s];
        }
        __syncthreads();
        signed char* kbb = tb + (size_t)(ic >> 5) * TILEB;
#pragma unroll
        for (int p = 0; p < 24; ++p) {
            const int idx = p * 256 + tid;
            const int kbi = idx >= 3072;
            const int ld  = idx - (kbi ? 3072 : 0);
            const int s  = ld >> 9;
            const int kc = (ld >> 8) & 1;
            const int r  = (ld >> 2) & 63;
            const int d4 = ld & 3;
            *(int*)&kbb[(size_t)kbi * TILEB + (size_t)ld * 4] =
                sldw[s][r][(kbi * 8 + kc * 4 + d4) ^ (r & 15)];
        }
        __syncthreads();
    }
}

// ---- pipelined int8 MFMA GEMM: 64x64 block, 4 waves of 32x32, depth-3 ----
__global__ __launch_bounds__(256, 2)
void snn_gemm_i8(const signed char* __restrict__ xp, const signed char* __restrict__ wp,
                 const float* __restrict__ sa, const float* __restrict__ sb,
                 double* __restrict__ cur, int t0, int tca, int ntiles)
{
    __shared__ signed char As[3][TILEB];   // 36 KB
    __shared__ signed char Bs[3][TILEB];   // 36 KB

    const int tid  = threadIdx.x;
    const int lane = tid & 63;
    const int wave = tid >> 6;
    const int wm = (wave >> 1) * 32;
    const int wn = (wave & 1) * 32;
    const int l31 = lane & 31;
    const int hi  = lane >> 5;

    // bijective XCD-aware remap (m204); nwg = 512*ntiles, always % 8 == 0
    int lid = blockIdx.x + (int)gridDim.x * (blockIdx.y + (int)gridDim.y * blockIdx.z);
    {
        const int nwg = (int)(gridDim.x * gridDim.y * gridDim.z);
        const int q = nwg >> 3, r = nwg & 7;
        const int xcd = lid & 7, off = lid >> 3;
        lid = (xcd < r ? xcd * (q + 1) : r * (q + 1) + (xcd - r) * q) + off;
    }
    const int ox  = lid & 15;          // o-tile (gridDim.x == 16)
    const int rst = lid >> 4;
    const int ty  = rst % ntiles;      // t-tile
    const int b   = rst / ntiles;      // batch

    const int o0 = ox * BO;
    const int bt = ty * BT;

    // Probe D reg->row (col is lane&31): A=I(32x32), B[k][n]=k => D[m][n]=m.
    int prow[16];
    {
        i32x4 pa, pb;
#pragma unroll
        for (int q = 0; q < 4; ++q) {
            int va = 0, vb = 0;
#pragma unroll
            for (int jj = 0; jj < 4; ++jj) {
                const int k = 16 * hi + q * 4 + jj;
                if (l31 == k) va |= 1 << (8 * jj);
                vb |= (k & 255) << (8 * jj);
            }
            pa[q] = va; pb[q] = vb;
        }
        i32x16 pp = (i32x16)0;
        pp = __builtin_amdgcn_mfma_i32_32x32x32_i8(pa, pb, pp, 0, 0, 0);
#pragma unroll
        for (int r = 0; r < 16; ++r) prow[r] = pp[r] & 31;
    }

    i32x16 acc[NS];
#pragma unroll
    for (int c = 0; c < NS; ++c) acc[c] = (i32x16)0;

    const signed char* Ag = xp + (size_t)(b * ntiles + ty) * (NKB * TILEB) + tid * 16;
    const signed char* Bg = wp + (size_t)ox * (NKB * TILEB) + tid * 16;
    signed char* Al = &As[0][0] + wave * 1024;   // wave-uniform LDS bases
    signed char* Bl = &Bs[0][0] + wave * 1024;

#define STAGE(src, bsel) do {                                                  \
    _Pragma("unroll")                                                          \
    for (int u = 0; u < 3; ++u) {                                              \
        GLDS16(Ag + (size_t)(src) * TILEB + u * 4096,                          \
               Al + (bsel) * TILEB + u * 4096);                                \
        GLDS16(Bg + (size_t)(src) * TILEB + u * 4096,                          \
               Bl + (bsel) * TILEB + u * 4096);                                \
    } } while (0)

    STAGE(0, 0);
    STAGE(1, 1);

    const int abase = hi * 1024 + (wm + l31) * 16;   // [kc=hi][row][16]
    const int bbase = hi * 1024 + (wn + l31) * 16;

    for (int kb = 0; kb < NKB; ++kb) {
        int src = kb + 2; if (src >= NKB) src -= NKB;   // tail wraps (harmless)
        STAGE(src, (kb + 2) % 3);
        // wait for stage(kb): 2 newer stages (12 loads/wave) stay in flight
        asm volatile("s_waitcnt vmcnt(12)" ::: "memory");
        __builtin_amdgcn_s_barrier();

        const signed char* Ab = &As[kb % 3][0];
        const signed char* Bb = &Bs[kb % 3][0];
        i32x4 af[NS], bf[NS];
#pragma unroll
        for (int s = 0; s < NS; ++s) {
            af[s] = *(const i32x4*)&Ab[abase + s * 2048];   // 512B contig / 32 lanes
            bf[s] = *(const i32x4*)&Bb[bbase + s * 2048];
        }
        // 21 slice pairs grouped by weight c=i+j into 6 accumulators
#pragma unroll
        for (int i = 0; i < NS; ++i)
#pragma unroll
            for (int c = NS - 1; c >= i; --c)
                acc[c] = __builtin_amdgcn_mfma_i32_32x32x32_i8(
                    af[i], bf[c - i], acc[c], 0, 0, 0);

        // reads must COMPLETE before any wave's next stage overwrites this buf
        asm volatile("s_waitcnt lgkmcnt(0)" ::: "memory");
        __builtin_amdgcn_sched_barrier(0);
        __builtin_amdgcn_s_barrier();
    }
#undef STAGE

    // epilogue: exact i32 partials -> fp64 currents
    const double c128[NS] = {0x1p-14, 0x1p-21, 0x1p-28, 0x1p-35, 0x1p-42, 0x1p-49};
    const int ocol = o0 + wn + l31;
    const double sbv = (double)sb[ocol];
#pragma unroll
    for (int r = 0; r < 16; ++r) {
        const int trow = bt + wm + prow[r];
        double v = 0.0;
#pragma unroll
        for (int c = 0; c < NS; ++c) v += (double)acc[c][r] * c128[c];
        v *= (double)sa[(size_t)b * tca + trow] * sbv;
        if (t0 + trow < NT)
            cur[((size_t)trow * NB + b) * NO + ocol] = v;
    }
}

// LIF scan: one thread per (b,o); cur chunk is [tc][b*NO+o] fp64. 32-step
// double buffer; 128B contiguous stores per thread per iter. (Unchanged, proven.)
#define NC 32
__global__ __launch_bounds__(64)
void snn_scan_f64(const double* __restrict__ cur, float* __restrict__ out,
                  double* __restrict__ vstate, int t0, int len)
{
    const int gid = blockIdx.x * 64 + threadIdx.x;   // b*NO + o
    const double dt = 0.001 / 50.0;                  // MS / TAU, IEEE double

    double v = (t0 == 0) ? 0.0 : vstate[gid];
    const double* cp = cur + gid;                    // stride NB*NO per t-step
    float* op = out + (size_t)gid * NT + t0;         // thread-contiguous in t

    const size_t ts = (size_t)NB * NO;               // 32768
    const int nb = len / NC;                         // full 32-blocks
    const int rem = len - nb * NC;                   // tail (multiple of 8)

    double A[NC], B[NC];
#pragma unroll
    for (int j = 0; j < NC; ++j) A[j] = (j < len) ? cp[(size_t)j * ts] : 0.0;

    for (int blk = 0; blk < nb; ++blk) {
        const int next = (blk + 1) * NC;
#pragma unroll
        for (int j = 0; j < NC; ++j)
            B[j] = (next + j < len) ? cp[(size_t)(next + j) * ts] : 0.0;

#pragma unroll
        for (int q = 0; q < NC; q += 8) {
            float s[8];
#pragma unroll
            for (int j = 0; j < 8; ++j) {
                v = v + (A[q + j] - v) * dt;
                const bool sp = (v >= 1.0);
                s[j] = sp ? 1.0f : 0.0f;
                if (sp) v = 0.0;
            }
            *(float4*)(op + q)     = make_float4(s[0], s[1], s[2], s[3]);
            *(float4*)(op + q + 4) = make_float4(s[4], s[5], s[6], s[7]);
        }
        op += NC;
#pragma unroll
        for (int j = 0; j < NC; ++j) A[j] = B[j];
    }

    for (int q = 0; q < rem; q += 8) {               // tail (data already in A)
        float s[8];
#pragma unroll
        for (int j = 0; j < 8; ++j) {
            v = v + (A[q + j] - v) * dt;
            const bool sp = (v >= 1.0);
            s[j] = sp ? 1.0f : 0.0f;
            if (sp) v = 0.0;
        }
        *(float4*)(op + q)     = make_float4(s[0], s[1], s[2], s[3]);
        *(float4*)(op + q + 4) = make_float4(s[4], s[5], s[6], s[7]);
    }
    vstate[gid] = v;
}

extern "C" void kernel_launch(void* const* d_in, const int* in_sizes, int n_in,
                              void* d_out, int out_size, void* d_ws, size_t ws_size,
                              hipStream_t stream)
{
    const float* x = (const float*)d_in[0];
    const float* w = (const float*)d_in[1];
    float* out = (float*)d_out;

    char* p = (char*)d_ws;
    double* vstate = (double*)p;         p += (size_t)NB * NO * 8;       // 256KB
    float* sbv = (float*)p;              p += (size_t)2 * NO * 4;        // 8KB
    signed char* wp = (signed char*)p;   p += (size_t)(NO / 64) * NKB * TILEB;  // 6MB

    const size_t fixed = (size_t)(p - (char*)d_ws);
    const size_t per_t = (size_t)NB * 4                // SA
                       + (size_t)NS * NB * NI          // x slices (tiled)
                       + (size_t)NB * NO * 8;          // cur
    int tca = 512;                                     // t-chunk, multiple of 64
    while (tca > 64 && fixed + (size_t)tca * per_t > ws_size) tca -= 64;

    float* sa = (float*)p;               p += (size_t)NB * tca * 4;
    signed char* xpl = (signed char*)p;  p += (size_t)NB * (tca / 64) * NKB * TILEB;
    double* cur = (double*)p;

    snn_wscale<<<dim3(NO / 64), dim3(256), 0, stream>>>(w, sbv);
    snn_wslice<<<dim3(NO / 64, NI / 64), dim3(256), 0, stream>>>(w, sbv, wp);

    for (int t0 = 0; t0 < NT; t0 += tca) {
        const int len = (NT - t0 < tca) ? (NT - t0) : tca;
        const int ntiles = (len + BT - 1) / BT;
        snn_xscale<<<dim3(ntiles, NB), dim3(256), 0, stream>>>(x, sa, t0, tca);
        snn_xslice<<<dim3(ntiles, NB, 4), dim3(256), 0, stream>>>(x, sa, xpl, t0, tca, ntiles);
        snn_gemm_i8<<<dim3(NO / BO, ntiles, NB), dim3(256), 0, stream>>>(
            xpl, wp, sa, sbv, cur, t0, tca, ntiles);
        snn_scan_f64<<<dim3((NB * NO) / 64), dim3(64), 0, stream>>>(
            cur, out, vstate, t0, len);
    }
}

// Round 4
// 1288.663 us; speedup vs baseline: 1.2526x; 1.0004x over previous
//
#include <hip/hip_runtime.h>

// SNN layer, round 11: int8 Ozaki GEMM + cross-iteration fragment prefetch.
//
//  r10b measured: bank-conflict 0, FETCH 250MB, but MfmaUtil STILL 41%
//  (396us/dispatch). Diagnosis: per-CU per k-iter, matrix pipe 1536cy and
//  LDS pipe 1152cy run SEQUENTIALLY (2-barrier lockstep: all waves ds_read,
//  then all MFMA) -> wall ~3700cy = m233's 2-phase stall. Neither HBM (61us
//  equiv) nor VALU (16%) nor conflicts (0) bind.
//
//  This round: register double-buffered fragments. While MFMAs(kb) run on
//  one frag set, ds_reads for kb+1 fill the other -> LDS pipe hides under
//  matrix pipe. ONE barrier per k-iter:
//    STAGE(kb+2) ; vmcnt(6) ; lgkmcnt(0) ; sched_barrier ; s_barrier ;
//    ds_read frags(kb+1) ; setprio(1) 21xMFMA setprio(0)
//  Race proof: reads of slot s issued post-barrier(j) are lgkm-drained
//  pre-barrier(j+1); DMA into s issues only post-barrier(j+1). vmcnt floor 6.
//  Even/odd unroll = compile-time frag sets (rule 20). T5 setprio now has
//  phase diversity (T3 satisfied).
//
//  Numerics unchanged from r9/r10 (absmax 0.0 proven): 6 slices, 21 pairs,
//  i32 exact, fp64 recombine. Prepasses + scan unchanged.
//
//  ws: vstate 256KB | SB 8KB | wp 6MB | SA | xp (tiled) | cur   (tca=512: 230MB)

#define NB 32
#define NI 1024
#define NO 1024
#define NT 1000
#define NS 6          // slices per operand (7 bits each, base 128)
#define BT 64         // t rows per block tile
#define BO 64         // o cols per block tile
#define KI 32         // k per pipeline stage
#define NKB (NI/KI)   // 32 k-blocks
#define TILEB (NS*2*64*16)   // 12288 B per (kb, matrix): [s][kc][row][16]

typedef int i32x4  __attribute__((ext_vector_type(4)));
typedef int i32x16 __attribute__((ext_vector_type(16)));

typedef const __attribute__((address_space(1))) void GVOID;
typedef __attribute__((address_space(3))) void LVOID;
#define GLDS16(g, l) __builtin_amdgcn_global_load_lds((GVOID*)(g), (LVOID*)(l), 16, 0, 0)

// ---- per-o column scale of w: SB = 2^(e+1) > colmax, plus 1/SB ----
__global__ void snn_wscale(const float* __restrict__ w, float* __restrict__ sb)
{
    __shared__ float red[4][64];
    const int tid = threadIdx.x;
    const int ol = tid & 63, iq = tid >> 6;
    const int o = blockIdx.x * 64 + ol;
    float m = 0.f;
    for (int i = iq; i < NI; i += 4) m = fmaxf(m, fabsf(w[(size_t)i * NO + o]));
    red[iq][ol] = m;
    __syncthreads();
    if (iq == 0) {
        m = fmaxf(fmaxf(red[0][ol], red[1][ol]), fmaxf(red[2][ol], red[3][ol]));
        const int e = (__float_as_uint(m) >> 23) & 255;
        float S = 0.f, Si = 0.f;
        if (e) {
            S  = __uint_as_float((unsigned)(e + 1) << 23);
            Si = __uint_as_float((unsigned)(253 - e) << 23);
        }
        sb[o] = S;
        sb[NO + o] = Si;
    }
}

// ---- slice w into tiled planes wp[otile][kb][s][kc][o][16] ----
__global__ void snn_wslice(const float* __restrict__ w, const float* __restrict__ sb,
                           signed char* __restrict__ wp)
{
    __shared__ int sldw[NS][64][16];   // XOR-swizzled dword cols (2-way max)
    const int tid = threadIdx.x;
    const int ol = tid & 63, iq = tid >> 6;
    const int o0 = blockIdx.x * 64, ic = blockIdx.y * 64;
    const float inv = sb[NO + o0 + ol];
#pragma unroll
    for (int q4 = 0; q4 < 16; q4 += 4) {
        int pk[NS] = {0, 0, 0, 0, 0, 0};
#pragma unroll
        for (int j = 0; j < 4; ++j) {
            const int i = ic + iq * 16 + q4 + j;
            float wv = w[(size_t)i * NO + o0 + ol] * inv;   // exact (pow2 scale)
#pragma unroll
            for (int s = 0; s < NS; ++s) {
                const float f = wv * 128.f;     // exact, |f|<128
                const int a = (int)f;           // trunc in [-127,127]
                wv = f - (float)a;              // exact remainder
                pk[s] |= (a & 255) << (8 * j);
            }
        }
        const int cdw = (iq * 16 + q4) >> 2;
#pragma unroll
        for (int s = 0; s < NS; ++s) sldw[s][ol][cdw ^ (ol & 15)] = pk[s];
    }
    __syncthreads();
    signed char* tb = wp + (size_t)blockIdx.x * (NKB * TILEB) + (size_t)(ic >> 5) * TILEB;
#pragma unroll
    for (int p = 0; p < 24; ++p) {       // 6144 dwords, contiguous per kb-half
        const int idx = p * 256 + tid;
        const int kbi = idx >= 3072;
        const int ld  = idx - (kbi ? 3072 : 0);
        const int s  = ld >> 9;
        const int kc = (ld >> 8) & 1;
        const int r  = (ld >> 2) & 63;
        const int d4 = ld & 3;
        *(int*)&tb[(size_t)kbi * TILEB + (size_t)ld * 4] =
            sldw[s][r][(kbi * 8 + kc * 4 + d4) ^ (r & 15)];
    }
}

// ---- per-(b,t) scale SA = 2^(e+1) > rowmax ----
__global__ void snn_xscale(const float* __restrict__ x, float* __restrict__ sa,
                           int t0, int tca)
{
    __shared__ float red[4][64];
    const int tid = threadIdx.x;
    const int tl = tid & 63, iq = tid >> 6;
    const int b = blockIdx.y;
    const int tt = blockIdx.x * 64;
    const int tg = t0 + tt + tl;
    const float* xb = x + (size_t)b * NI * NT;
    float m = 0.f;
    if (tg < NT)
        for (int i = iq; i < NI; i += 4) m = fmaxf(m, fabsf(xb[(size_t)i * NT + tg]));
    red[iq][tl] = m;
    __syncthreads();
    if (iq == 0) {
        m = fmaxf(fmaxf(red[0][tl], red[1][tl]), fmaxf(red[2][tl], red[3][tl]));
        const int e = (__float_as_uint(m) >> 23) & 255;
        sa[(size_t)b * tca + tt + tl] = e ? __uint_as_float((unsigned)(e + 1) << 23) : 0.f;
    }
}

// ---- slice x into tiled planes xp[b][tile][kb][s][kc][t][16] ----
__global__ void snn_xslice(const float* __restrict__ x, const float* __restrict__ sa,
                           signed char* __restrict__ xp, int t0, int tca, int ntiles)
{
    __shared__ int sldw[NS][64][16];
    const int tid = threadIdx.x;
    const int tl = tid & 63, iq = tid >> 6;
    const int b = blockIdx.y;
    const int tile = blockIdx.x;
    const int tg = t0 + tile * 64 + tl;
    const bool valid = (tg < NT);
    const float* xb = x + (size_t)b * NI * NT;
    const float S = sa[(size_t)b * tca + tile * 64 + tl];
    const float inv = (S > 0.f)
        ? __uint_as_float((254u - (__float_as_uint(S) >> 23)) << 23) : 0.f;  // exact 1/S
    signed char* tb = xp + (size_t)(b * ntiles + tile) * (NKB * TILEB);

    for (int c4 = 0; c4 < 4; ++c4) {
        const int ic = blockIdx.z * 256 + c4 * 64;
#pragma unroll
        for (int q4 = 0; q4 < 16; q4 += 4) {
            int pk[NS] = {0, 0, 0, 0, 0, 0};
#pragma unroll
            for (int j = 0; j < 4; ++j) {
                const int i = ic + iq * 16 + q4 + j;
                float wv = valid ? xb[(size_t)i * NT + tg] * inv : 0.f;
#pragma unroll
                for (int s = 0; s < NS; ++s) {
                    const float f = wv * 128.f;
                    const int a = (int)f;
                    wv = f - (float)a;
                    pk[s] |= (a & 255) << (8 * j);
                }
            }
            const int cdw = (iq * 16 + q4) >> 2;
#pragma unroll
            for (int s = 0; s < NS; ++s) sldw[s][tl][cdw ^ (tl & 15)] = pk[s];
        }
        __syncthreads();
        signed char* kbb = tb + (size_t)(ic >> 5) * TILEB;
#pragma unroll
        for (int p = 0; p < 24; ++p) {
            const int idx = p * 256 + tid;
            const int kbi = idx >= 3072;
            const int ld  = idx - (kbi ? 3072 : 0);
            const int s  = ld >> 9;
            const int kc = (ld >> 8) & 1;
            const int r  = (ld >> 2) & 63;
            const int d4 = ld & 3;
            *(int*)&kbb[(size_t)kbi * TILEB + (size_t)ld * 4] =
                sldw[s][r][(kbi * 8 + kc * 4 + d4) ^ (r & 15)];
        }
        __syncthreads();
    }
}

// ---- pipelined int8 MFMA GEMM: 64x64 block, 4 waves of 32x32 ----
// depth-3 LDS DMA pipeline + register double-buffered fragments:
// LDS reads for kb+1 overlap the 21 MFMAs of kb; one barrier per k-iter.
__global__ __launch_bounds__(256, 2)
void snn_gemm_i8(const signed char* __restrict__ xp, const signed char* __restrict__ wp,
                 const float* __restrict__ sa, const float* __restrict__ sb,
                 double* __restrict__ cur, int t0, int tca, int ntiles)
{
    __shared__ signed char As[3][TILEB];   // 36 KB
    __shared__ signed char Bs[3][TILEB];   // 36 KB

    const int tid  = threadIdx.x;
    const int lane = tid & 63;
    const int wave = tid >> 6;
    const int wm = (wave >> 1) * 32;
    const int wn = (wave & 1) * 32;
    const int l31 = lane & 31;
    const int hi  = lane >> 5;

    // bijective XCD-aware remap (m204); nwg = 512*ntiles, always % 8 == 0
    int lid = blockIdx.x + (int)gridDim.x * (blockIdx.y + (int)gridDim.y * blockIdx.z);
    {
        const int nwg = (int)(gridDim.x * gridDim.y * gridDim.z);
        const int q = nwg >> 3, r = nwg & 7;
        const int xcd = lid & 7, off = lid >> 3;
        lid = (xcd < r ? xcd * (q + 1) : r * (q + 1) + (xcd - r) * q) + off;
    }
    const int ox  = lid & 15;          // o-tile (gridDim.x == 16)
    const int rst = lid >> 4;
    const int ty  = rst % ntiles;      // t-tile
    const int b   = rst / ntiles;      // batch

    const int o0 = ox * BO;
    const int bt = ty * BT;

    // Probe D reg->row (col is lane&31): A=I(32x32), B[k][n]=k => D[m][n]=m.
    int prow[16];
    {
        i32x4 pa, pb;
#pragma unroll
        for (int q = 0; q < 4; ++q) {
            int va = 0, vb = 0;
#pragma unroll
            for (int jj = 0; jj < 4; ++jj) {
                const int k = 16 * hi + q * 4 + jj;
                if (l31 == k) va |= 1 << (8 * jj);
                vb |= (k & 255) << (8 * jj);
            }
            pa[q] = va; pb[q] = vb;
        }
        i32x16 pp = (i32x16)0;
        pp = __builtin_amdgcn_mfma_i32_32x32x32_i8(pa, pb, pp, 0, 0, 0);
#pragma unroll
        for (int r = 0; r < 16; ++r) prow[r] = pp[r] & 31;
    }

    i32x16 acc[NS];
#pragma unroll
    for (int c = 0; c < NS; ++c) acc[c] = (i32x16)0;

    const signed char* Ag = xp + (size_t)(b * ntiles + ty) * (NKB * TILEB) + tid * 16;
    const signed char* Bg = wp + (size_t)ox * (NKB * TILEB) + tid * 16;
    signed char* Al = &As[0][0] + wave * 1024;   // wave-uniform LDS bases
    signed char* Bl = &Bs[0][0] + wave * 1024;

#define STAGE(src, bsel) do {                                                  \
    _Pragma("unroll")                                                          \
    for (int u = 0; u < 3; ++u) {                                              \
        GLDS16(Ag + (size_t)(src) * TILEB + u * 4096,                          \
               Al + (bsel) * TILEB + u * 4096);                                \
        GLDS16(Bg + (size_t)(src) * TILEB + u * 4096,                          \
               Bl + (bsel) * TILEB + u * 4096);                                \
    } } while (0)

    const int abase = hi * 1024 + (wm + l31) * 16;   // [kc=hi][row][16]
    const int bbase = hi * 1024 + (wn + l31) * 16;

#define LDFRAG(fa, fb, slot) do {                                              \
    const signed char* Ab_ = &As[slot][0];                                     \
    const signed char* Bb_ = &Bs[slot][0];                                     \
    _Pragma("unroll")                                                          \
    for (int s = 0; s < NS; ++s) {                                             \
        fa[s] = *(const i32x4*)&Ab_[abase + s * 2048];                         \
        fb[s] = *(const i32x4*)&Bb_[bbase + s * 2048];                         \
    } } while (0)

#define MFMAS(fa, fb) do {                                                     \
    __builtin_amdgcn_s_setprio(1);                                             \
    _Pragma("unroll")                                                          \
    for (int i = 0; i < NS; ++i)                                               \
    _Pragma("unroll")                                                          \
    for (int c = NS - 1; c >= i; --c)                                          \
        acc[c] = __builtin_amdgcn_mfma_i32_32x32x32_i8(fa[i], fb[c - i],       \
                                                       acc[c], 0, 0, 0);       \
    __builtin_amdgcn_s_setprio(0);                                             \
    } while (0)

    // sync point: drain own ds_reads (issued post-previous-barrier), then
    // barrier; only after THIS barrier may any wave's new DMA touch the slot
    // those reads used (m152/rule-18 discipline).
#define SYNC() do {                                                            \
    asm volatile("s_waitcnt vmcnt(6)" ::: "memory");                           \
    asm volatile("s_waitcnt lgkmcnt(0)" ::: "memory");                         \
    __builtin_amdgcn_sched_barrier(0);                                         \
    __builtin_amdgcn_s_barrier();                                              \
    } while (0)

    i32x4 fa0[NS], fb0[NS], fa1[NS], fb1[NS];

    // prologue: stage 0,1; read frags(0)
    STAGE(0, 0);
    STAGE(1, 1);
    asm volatile("s_waitcnt vmcnt(6)" ::: "memory");   // stage 0 complete
    __builtin_amdgcn_s_barrier();
    LDFRAG(fa0, fb0, 0);

    int src = 2;        // next k-block to stage
    int st  = 2;        // its slot ((kb+2)%3)
    int rd  = 1;        // slot of frags(kb+1)
    for (int kb = 0; kb < NKB; kb += 2) {
        // even: compute frags(kb) [set 0], read frags(kb+1) into set 1
        STAGE(src, st);
        src = (src + 1 >= NKB) ? 0 : src + 1;
        st  = (st == 2) ? 0 : st + 1;
        SYNC();
        LDFRAG(fa1, fb1, rd);
        rd  = (rd == 2) ? 0 : rd + 1;
        MFMAS(fa0, fb0);
        // odd: compute frags(kb+1) [set 1], read frags(kb+2) into set 0
        STAGE(src, st);
        src = (src + 1 >= NKB) ? 0 : src + 1;
        st  = (st == 2) ? 0 : st + 1;
        SYNC();
        LDFRAG(fa0, fb0, rd);
        rd  = (rd == 2) ? 0 : rd + 1;
        MFMAS(fa1, fb1);
    }
#undef STAGE
#undef LDFRAG
#undef MFMAS
#undef SYNC

    // epilogue: exact i32 partials -> fp64 currents
    const double c128[NS] = {0x1p-14, 0x1p-21, 0x1p-28, 0x1p-35, 0x1p-42, 0x1p-49};
    const int ocol = o0 + wn + l31;
    const double sbv = (double)sb[ocol];
#pragma unroll
    for (int r = 0; r < 16; ++r) {
        const int trow = bt + wm + prow[r];
        double v = 0.0;
#pragma unroll
        for (int c = 0; c < NS; ++c) v += (double)acc[c][r] * c128[c];
        v *= (double)sa[(size_t)b * tca + trow] * sbv;
        if (t0 + trow < NT)
            cur[((size_t)trow * NB + b) * NO + ocol] = v;
    }
}

// LIF scan: one thread per (b,o); cur chunk is [tc][b*NO+o] fp64. 32-step
// double buffer; 128B contiguous stores per thread per iter. (Unchanged, proven.)
#define NC 32
__global__ __launch_bounds__(64)
void snn_scan_f64(const double* __restrict__ cur, float* __restrict__ out,
                  double* __restrict__ vstate, int t0, int len)
{
    const int gid = blockIdx.x * 64 + threadIdx.x;   // b*NO + o
    const double dt = 0.001 / 50.0;                  // MS / TAU, IEEE double

    double v = (t0 == 0) ? 0.0 : vstate[gid];
    const double* cp = cur + gid;                    // stride NB*NO per t-step
    float* op = out + (size_t)gid * NT + t0;         // thread-contiguous in t

    const size_t ts = (size_t)NB * NO;               // 32768
    const int nb = len / NC;                         // full 32-blocks
    const int rem = len - nb * NC;                   // tail (multiple of 8)

    double A[NC], B[NC];
#pragma unroll
    for (int j = 0; j < NC; ++j) A[j] = (j < len) ? cp[(size_t)j * ts] : 0.0;

    for (int blk = 0; blk < nb; ++blk) {
        const int next = (blk + 1) * NC;
#pragma unroll
        for (int j = 0; j < NC; ++j)
            B[j] = (next + j < len) ? cp[(size_t)(next + j) * ts] : 0.0;

#pragma unroll
        for (int q = 0; q < NC; q += 8) {
            float s[8];
#pragma unroll
            for (int j = 0; j < 8; ++j) {
                v = v + (A[q + j] - v) * dt;
                const bool sp = (v >= 1.0);
                s[j] = sp ? 1.0f : 0.0f;
                if (sp) v = 0.0;
            }
            *(float4*)(op + q)     = make_float4(s[0], s[1], s[2], s[3]);
            *(float4*)(op + q + 4) = make_float4(s[4], s[5], s[6], s[7]);
        }
        op += NC;
#pragma unroll
        for (int j = 0; j < NC; ++j) A[j] = B[j];
    }

    for (int q = 0; q < rem; q += 8) {               // tail (data already in A)
        float s[8];
#pragma unroll
        for (int j = 0; j < 8; ++j) {
            v = v + (A[q + j] - v) * dt;
            const bool sp = (v >= 1.0);
            s[j] = sp ? 1.0f : 0.0f;
            if (sp) v = 0.0;
        }
        *(float4*)(op + q)     = make_float4(s[0], s[1], s[2], s[3]);
        *(float4*)(op + q + 4) = make_float4(s[4], s[5], s[6], s[7]);
    }
    vstate[gid] = v;
}

extern "C" void kernel_launch(void* const* d_in, const int* in_sizes, int n_in,
                              void* d_out, int out_size, void* d_ws, size_t ws_size,
                              hipStream_t stream)
{
    const float* x = (const float*)d_in[0];
    const float* w = (const float*)d_in[1];
    float* out = (float*)d_out;

    char* p = (char*)d_ws;
    double* vstate = (double*)p;         p += (size_t)NB * NO * 8;       // 256KB
    float* sbv = (float*)p;              p += (size_t)2 * NO * 4;        // 8KB
    signed char* wp = (signed char*)p;   p += (size_t)(NO / 64) * NKB * TILEB;  // 6MB

    const size_t fixed = (size_t)(p - (char*)d_ws);
    const size_t per_t = (size_t)NB * 4                // SA
                       + (size_t)NS * NB * NI          // x slices (tiled)
                       + (size_t)NB * NO * 8;          // cur
    int tca = 512;                                     // t-chunk, multiple of 64
    while (tca > 64 && fixed + (size_t)tca * per_t > ws_size) tca -= 64;

    float* sa = (float*)p;               p += (size_t)NB * tca * 4;
    signed char* xpl = (signed char*)p;  p += (size_t)NB * (tca / 64) * NKB * TILEB;
    double* cur = (double*)p;

    snn_wscale<<<dim3(NO / 64), dim3(256), 0, stream>>>(w, sbv);
    snn_wslice<<<dim3(NO / 64, NI / 64), dim3(256), 0, stream>>>(w, sbv, wp);

    for (int t0 = 0; t0 < NT; t0 += tca) {
        const int len = (NT - t0 < tca) ? (NT - t0) : tca;
        const int ntiles = (len + BT - 1) / BT;
        snn_xscale<<<dim3(ntiles, NB), dim3(256), 0, stream>>>(x, sa, t0, tca);
        snn_xslice<<<dim3(ntiles, NB, 4), dim3(256), 0, stream>>>(x, sa, xpl, t0, tca, ntiles);
        snn_gemm_i8<<<dim3(NO / BO, ntiles, NB), dim3(256), 0, stream>>>(
            xpl, wp, sa, sbv, cur, t0, tca, ntiles);
        snn_scan_f64<<<dim3((NB * NO) / 64), dim3(64), 0, stream>>>(
            cur, out, vstate, t0, len);
    }
}

// Round 5
// 1208.869 us; speedup vs baseline: 1.3353x; 1.0660x over previous
//
#include <hip/hip_runtime.h>

// SNN layer, round 12: int8 Ozaki GEMM — occupancy experiment (2->3 blocks/CU).
//
//  Evidence: r9 (reg-staging, 5e7 conflicts), r10b (DMA, 0 conflicts), r11
//  (reg-dbuf frags, 1 barrier) -- THREE schedules, identical 398us / 41%
//  MfmaUtil / 23% occupancy. Schedule is exonerated; the invariant is
//  2 blocks/CU (LDS 72KB). i8 MFMA needs more in-flight waves than f64
//  (9 cy/instr vs 64): at 2 waves/SIMD any issue gap un-feeds the pipe.
//
//  This round: LDS 48KB (2 slots x 24KB), __launch_bounds__(256,3),
//  register diet (probe moved to epilogue, rolling A-frag loads) ->
//  3 blocks/CU. Race-free 1-barrier loop:
//    B(kb); STAGE(kb+1 -> slot^1)   [that slot's reads drained pre-B(kb)]
//    LDFRAG(slot kb)                [DMA(kb) vmcnt-drained pre-B(kb)]
//    MFMAs; vmcnt(0) (hidden under cluster); lgkmcnt(0); B(kb+1)
//
//  Numerics unchanged (absmax 0.0 proven): 6 slices base-128, 21 pairs
//  grouped into 6 i32 accs, fp64 recombine. Prepasses + scan unchanged.
//
//  ws: vstate 256KB | SB 8KB | wp 6MB | SA | xp (tiled) | cur  (tca=512: 230MB)

#define NB 32
#define NI 1024
#define NO 1024
#define NT 1000
#define NS 6          // slices per operand (7 bits each, base 128)
#define BT 64         // t rows per block tile
#define BO 64         // o cols per block tile
#define KI 32         // k per pipeline stage
#define NKB (NI/KI)   // 32 k-blocks
#define TILEB (NS*2*64*16)   // 12288 B per (kb, matrix): [s][kc][row][16]

typedef int i32x4  __attribute__((ext_vector_type(4)));
typedef int i32x16 __attribute__((ext_vector_type(16)));

typedef const __attribute__((address_space(1))) void GVOID;
typedef __attribute__((address_space(3))) void LVOID;
#define GLDS16(g, l) __builtin_amdgcn_global_load_lds((GVOID*)(g), (LVOID*)(l), 16, 0, 0)

// ---- per-o column scale of w: SB = 2^(e+1) > colmax, plus 1/SB ----
__global__ void snn_wscale(const float* __restrict__ w, float* __restrict__ sb)
{
    __shared__ float red[4][64];
    const int tid = threadIdx.x;
    const int ol = tid & 63, iq = tid >> 6;
    const int o = blockIdx.x * 64 + ol;
    float m = 0.f;
    for (int i = iq; i < NI; i += 4) m = fmaxf(m, fabsf(w[(size_t)i * NO + o]));
    red[iq][ol] = m;
    __syncthreads();
    if (iq == 0) {
        m = fmaxf(fmaxf(red[0][ol], red[1][ol]), fmaxf(red[2][ol], red[3][ol]));
        const int e = (__float_as_uint(m) >> 23) & 255;
        float S = 0.f, Si = 0.f;
        if (e) {
            S  = __uint_as_float((unsigned)(e + 1) << 23);
            Si = __uint_as_float((unsigned)(253 - e) << 23);
        }
        sb[o] = S;
        sb[NO + o] = Si;
    }
}

// ---- slice w into tiled planes wp[otile][kb][s][kc][o][16] ----
__global__ void snn_wslice(const float* __restrict__ w, const float* __restrict__ sb,
                           signed char* __restrict__ wp)
{
    __shared__ int sldw[NS][64][16];   // XOR-swizzled dword cols (2-way max)
    const int tid = threadIdx.x;
    const int ol = tid & 63, iq = tid >> 6;
    const int o0 = blockIdx.x * 64, ic = blockIdx.y * 64;
    const float inv = sb[NO + o0 + ol];
#pragma unroll
    for (int q4 = 0; q4 < 16; q4 += 4) {
        int pk[NS] = {0, 0, 0, 0, 0, 0};
#pragma unroll
        for (int j = 0; j < 4; ++j) {
            const int i = ic + iq * 16 + q4 + j;
            float wv = w[(size_t)i * NO + o0 + ol] * inv;   // exact (pow2 scale)
#pragma unroll
            for (int s = 0; s < NS; ++s) {
                const float f = wv * 128.f;     // exact, |f|<128
                const int a = (int)f;           // trunc in [-127,127]
                wv = f - (float)a;              // exact remainder
                pk[s] |= (a & 255) << (8 * j);
            }
        }
        const int cdw = (iq * 16 + q4) >> 2;
#pragma unroll
        for (int s = 0; s < NS; ++s) sldw[s][ol][cdw ^ (ol & 15)] = pk[s];
    }
    __syncthreads();
    signed char* tb = wp + (size_t)blockIdx.x * (NKB * TILEB) + (size_t)(ic >> 5) * TILEB;
#pragma unroll
    for (int p = 0; p < 24; ++p) {       // 6144 dwords, contiguous per kb-half
        const int idx = p * 256 + tid;
        const int kbi = idx >= 3072;
        const int ld  = idx - (kbi ? 3072 : 0);
        const int s  = ld >> 9;
        const int kc = (ld >> 8) & 1;
        const int r  = (ld >> 2) & 63;
        const int d4 = ld & 3;
        *(int*)&tb[(size_t)kbi * TILEB + (size_t)ld * 4] =
            sldw[s][r][(kbi * 8 + kc * 4 + d4) ^ (r & 15)];
    }
}

// ---- per-(b,t) scale SA = 2^(e+1) > rowmax ----
__global__ void snn_xscale(const float* __restrict__ x, float* __restrict__ sa,
                           int t0, int tca)
{
    __shared__ float red[4][64];
    const int tid = threadIdx.x;
    const int tl = tid & 63, iq = tid >> 6;
    const int b = blockIdx.y;
    const int tt = blockIdx.x * 64;
    const int tg = t0 + tt + tl;
    const float* xb = x + (size_t)b * NI * NT;
    float m = 0.f;
    if (tg < NT)
        for (int i = iq; i < NI; i += 4) m = fmaxf(m, fabsf(xb[(size_t)i * NT + tg]));
    red[iq][tl] = m;
    __syncthreads();
    if (iq == 0) {
        m = fmaxf(fmaxf(red[0][tl], red[1][tl]), fmaxf(red[2][tl], red[3][tl]));
        const int e = (__float_as_uint(m) >> 23) & 255;
        sa[(size_t)b * tca + tt + tl] = e ? __uint_as_float((unsigned)(e + 1) << 23) : 0.f;
    }
}

// ---- slice x into tiled planes xp[b][tile][kb][s][kc][t][16] ----
__global__ void snn_xslice(const float* __restrict__ x, const float* __restrict__ sa,
                           signed char* __restrict__ xp, int t0, int tca, int ntiles)
{
    __shared__ int sldw[NS][64][16];
    const int tid = threadIdx.x;
    const int tl = tid & 63, iq = tid >> 6;
    const int b = blockIdx.y;
    const int tile = blockIdx.x;
    const int tg = t0 + tile * 64 + tl;
    const bool valid = (tg < NT);
    const float* xb = x + (size_t)b * NI * NT;
    const float S = sa[(size_t)b * tca + tile * 64 + tl];
    const float inv = (S > 0.f)
        ? __uint_as_float((254u - (__float_as_uint(S) >> 23)) << 23) : 0.f;  // exact 1/S
    signed char* tb = xp + (size_t)(b * ntiles + tile) * (NKB * TILEB);

    for (int c4 = 0; c4 < 4; ++c4) {
        const int ic = blockIdx.z * 256 + c4 * 64;
#pragma unroll
        for (int q4 = 0; q4 < 16; q4 += 4) {
            int pk[NS] = {0, 0, 0, 0, 0, 0};
#pragma unroll
            for (int j = 0; j < 4; ++j) {
                const int i = ic + iq * 16 + q4 + j;
                float wv = valid ? xb[(size_t)i * NT + tg] * inv : 0.f;
#pragma unroll
                for (int s = 0; s < NS; ++s) {
                    const float f = wv * 128.f;
                    const int a = (int)f;
                    wv = f - (float)a;
                    pk[s] |= (a & 255) << (8 * j);
                }
            }
            const int cdw = (iq * 16 + q4) >> 2;
#pragma unroll
            for (int s = 0; s < NS; ++s) sldw[s][tl][cdw ^ (tl & 15)] = pk[s];
        }
        __syncthreads();
        signed char* kbb = tb + (size_t)(ic >> 5) * TILEB;
#pragma unroll
        for (int p = 0; p < 24; ++p) {
            const int idx = p * 256 + tid;
            const int kbi = idx >= 3072;
            const int ld  = idx - (kbi ? 3072 : 0);
            const int s  = ld >> 9;
            const int kc = (ld >> 8) & 1;
            const int r  = (ld >> 2) & 63;
            const int d4 = ld & 3;
            *(int*)&kbb[(size_t)kbi * TILEB + (size_t)ld * 4] =
                sldw[s][r][(kbi * 8 + kc * 4 + d4) ^ (r & 15)];
        }
        __syncthreads();
    }
}

// ---- pipelined int8 MFMA GEMM: 64x64 block, 4 waves of 32x32 ----
// 2-slot LDS double buffer (48KB -> 3 blocks/CU), one barrier per k-iter,
// vmcnt(0) hidden under the MFMA cluster, rolling A-frag reads.
__global__ __launch_bounds__(256, 3)
void snn_gemm_i8(const signed char* __restrict__ xp, const signed char* __restrict__ wp,
                 const float* __restrict__ sa, const float* __restrict__ sb,
                 double* __restrict__ cur, int t0, int tca, int ntiles)
{
    __shared__ signed char As[2][TILEB];   // 24 KB
    __shared__ signed char Bs[2][TILEB];   // 24 KB

    const int tid  = threadIdx.x;
    const int lane = tid & 63;
    const int wave = tid >> 6;
    const int wm = (wave >> 1) * 32;
    const int wn = (wave & 1) * 32;
    const int l31 = lane & 31;
    const int hi  = lane >> 5;

    // bijective XCD-aware remap (m204); nwg = 512*ntiles, always % 8 == 0
    int lid = blockIdx.x + (int)gridDim.x * (blockIdx.y + (int)gridDim.y * blockIdx.z);
    {
        const int nwg = (int)(gridDim.x * gridDim.y * gridDim.z);
        const int q = nwg >> 3, r = nwg & 7;
        const int xcd = lid & 7, off = lid >> 3;
        lid = (xcd < r ? xcd * (q + 1) : r * (q + 1) + (xcd - r) * q) + off;
    }
    const int ox  = lid & 15;          // o-tile (gridDim.x == 16)
    const int rst = lid >> 4;
    const int ty  = rst % ntiles;      // t-tile
    const int b   = rst / ntiles;      // batch

    const int o0 = ox * BO;
    const int bt = ty * BT;

    i32x16 acc[NS];
#pragma unroll
    for (int c = 0; c < NS; ++c) acc[c] = (i32x16)0;

    const signed char* Ag = xp + (size_t)(b * ntiles + ty) * (NKB * TILEB) + tid * 16;
    const signed char* Bg = wp + (size_t)ox * (NKB * TILEB) + tid * 16;
    signed char* Al = &As[0][0] + wave * 1024;   // wave-uniform LDS bases
    signed char* Bl = &Bs[0][0] + wave * 1024;

#define STAGE(src, bsel) do {                                                  \
    _Pragma("unroll")                                                          \
    for (int u = 0; u < 3; ++u) {                                              \
        GLDS16(Ag + (size_t)(src) * TILEB + u * 4096,                          \
               Al + (bsel) * TILEB + u * 4096);                                \
        GLDS16(Bg + (size_t)(src) * TILEB + u * 4096,                          \
               Bl + (bsel) * TILEB + u * 4096);                                \
    } } while (0)

    const int abase = hi * 1024 + (wm + l31) * 16;   // [kc=hi][row][16]
    const int bbase = hi * 1024 + (wn + l31) * 16;

    // one k-iteration: read B frags + rolling A frags, 21 MFMAs (6 weight-
    // grouped accumulators). A-frag i+1 load issues before group i's MFMAs
    // -> ~220cy of cover per read.
#define KITER(slot) do {                                                       \
    const signed char* Ab_ = &As[slot][0];                                     \
    const signed char* Bb_ = &Bs[slot][0];                                     \
    i32x4 bf[NS];                                                              \
    _Pragma("unroll")                                                          \
    for (int s = 0; s < NS; ++s) bf[s] = *(const i32x4*)&Bb_[bbase + s * 2048];\
    i32x4 a0 = *(const i32x4*)&Ab_[abase];                                     \
    _Pragma("unroll")                                                          \
    for (int i = 0; i < NS; ++i) {                                             \
        i32x4 a1 = a0;                                                         \
        if (i + 1 < NS) a1 = *(const i32x4*)&Ab_[abase + (i + 1) * 2048];      \
        __builtin_amdgcn_s_setprio(1);                                         \
        _Pragma("unroll")                                                      \
        for (int c = NS - 1; c >= i; --c)                                      \
            acc[c] = __builtin_amdgcn_mfma_i32_32x32x32_i8(a0, bf[c - i],      \
                                                           acc[c], 0, 0, 0);   \
        __builtin_amdgcn_s_setprio(0);                                         \
        a0 = a1;                                                               \
    } } while (0)

    // prologue: DMA(0) complete everywhere before first reads
    STAGE(0, 0);
    asm volatile("s_waitcnt vmcnt(0)" ::: "memory");
    __builtin_amdgcn_s_barrier();

    for (int kb = 0; kb < NKB - 1; ++kb) {
        // post-B(kb): all waves' reads of slot[(kb+1)&1] (iter kb-1) drained
        STAGE(kb + 1, (kb + 1) & 1);
        KITER(kb & 1);
        // DMA(kb+1) complete + own ds_reads drained before B(kb+1)
        asm volatile("s_waitcnt vmcnt(0)" ::: "memory");
        asm volatile("s_waitcnt lgkmcnt(0)" ::: "memory");
        __builtin_amdgcn_sched_barrier(0);
        __builtin_amdgcn_s_barrier();
    }
    KITER((NKB - 1) & 1);   // last k-block: nothing to stage
#undef STAGE
#undef KITER

    // Probe D reg->row mapping (epilogue: keeps 16 regs out of the main loop).
    // A=I(32x32), B[k][n]=k => D[m][n]=m (col is lane&31).
    int prow[16];
    {
        i32x4 pa, pb;
#pragma unroll
        for (int q = 0; q < 4; ++q) {
            int va = 0, vb = 0;
#pragma unroll
            for (int jj = 0; jj < 4; ++jj) {
                const int k = 16 * hi + q * 4 + jj;
                if (l31 == k) va |= 1 << (8 * jj);
                vb |= (k & 255) << (8 * jj);
            }
            pa[q] = va; pb[q] = vb;
        }
        i32x16 pp = (i32x16)0;
        pp = __builtin_amdgcn_mfma_i32_32x32x32_i8(pa, pb, pp, 0, 0, 0);
#pragma unroll
        for (int r = 0; r < 16; ++r) prow[r] = pp[r] & 31;
    }

    // epilogue: exact i32 partials -> fp64 currents
    const double c128[NS] = {0x1p-14, 0x1p-21, 0x1p-28, 0x1p-35, 0x1p-42, 0x1p-49};
    const int ocol = o0 + wn + l31;
    const double sbv = (double)sb[ocol];
#pragma unroll
    for (int r = 0; r < 16; ++r) {
        const int trow = bt + wm + prow[r];
        double v = 0.0;
#pragma unroll
        for (int c = 0; c < NS; ++c) v += (double)acc[c][r] * c128[c];
        v *= (double)sa[(size_t)b * tca + trow] * sbv;
        if (t0 + trow < NT)
            cur[((size_t)trow * NB + b) * NO + ocol] = v;
    }
}

// LIF scan: one thread per (b,o); cur chunk is [tc][b*NO+o] fp64. 32-step
// double buffer; 128B contiguous stores per thread per iter. (Unchanged, proven.)
#define NC 32
__global__ __launch_bounds__(64)
void snn_scan_f64(const double* __restrict__ cur, float* __restrict__ out,
                  double* __restrict__ vstate, int t0, int len)
{
    const int gid = blockIdx.x * 64 + threadIdx.x;   // b*NO + o
    const double dt = 0.001 / 50.0;                  // MS / TAU, IEEE double

    double v = (t0 == 0) ? 0.0 : vstate[gid];
    const double* cp = cur + gid;                    // stride NB*NO per t-step
    float* op = out + (size_t)gid * NT + t0;         // thread-contiguous in t

    const size_t ts = (size_t)NB * NO;               // 32768
    const int nb = len / NC;                         // full 32-blocks
    const int rem = len - nb * NC;                   // tail (multiple of 8)

    double A[NC], B[NC];
#pragma unroll
    for (int j = 0; j < NC; ++j) A[j] = (j < len) ? cp[(size_t)j * ts] : 0.0;

    for (int blk = 0; blk < nb; ++blk) {
        const int next = (blk + 1) * NC;
#pragma unroll
        for (int j = 0; j < NC; ++j)
            B[j] = (next + j < len) ? cp[(size_t)(next + j) * ts] : 0.0;

#pragma unroll
        for (int q = 0; q < NC; q += 8) {
            float s[8];
#pragma unroll
            for (int j = 0; j < 8; ++j) {
                v = v + (A[q + j] - v) * dt;
                const bool sp = (v >= 1.0);
                s[j] = sp ? 1.0f : 0.0f;
                if (sp) v = 0.0;
            }
            *(float4*)(op + q)     = make_float4(s[0], s[1], s[2], s[3]);
            *(float4*)(op + q + 4) = make_float4(s[4], s[5], s[6], s[7]);
        }
        op += NC;
#pragma unroll
        for (int j = 0; j < NC; ++j) A[j] = B[j];
    }

    for (int q = 0; q < rem; q += 8) {               // tail (data already in A)
        float s[8];
#pragma unroll
        for (int j = 0; j < 8; ++j) {
            v = v + (A[q + j] - v) * dt;
            const bool sp = (v >= 1.0);
            s[j] = sp ? 1.0f : 0.0f;
            if (sp) v = 0.0;
        }
        *(float4*)(op + q)     = make_float4(s[0], s[1], s[2], s[3]);
        *(float4*)(op + q + 4) = make_float4(s[4], s[5], s[6], s[7]);
    }
    vstate[gid] = v;
}

extern "C" void kernel_launch(void* const* d_in, const int* in_sizes, int n_in,
                              void* d_out, int out_size, void* d_ws, size_t ws_size,
                              hipStream_t stream)
{
    const float* x = (const float*)d_in[0];
    const float* w = (const float*)d_in[1];
    float* out = (float*)d_out;

    char* p = (char*)d_ws;
    double* vstate = (double*)p;         p += (size_t)NB * NO * 8;       // 256KB
    float* sbv = (float*)p;              p += (size_t)2 * NO * 4;        // 8KB
    signed char* wp = (signed char*)p;   p += (size_t)(NO / 64) * NKB * TILEB;  // 6MB

    const size_t fixed = (size_t)(p - (char*)d_ws);
    const size_t per_t = (size_t)NB * 4                // SA
                       + (size_t)NS * NB * NI          // x slices (tiled)
                       + (size_t)NB * NO * 8;          // cur
    int tca = 512;                                     // t-chunk, multiple of 64
    while (tca > 64 && fixed + (size_t)tca * per_t > ws_size) tca -= 64;

    float* sa = (float*)p;               p += (size_t)NB * tca * 4;
    signed char* xpl = (signed char*)p;  p += (size_t)NB * (tca / 64) * NKB * TILEB;
    double* cur = (double*)p;

    snn_wscale<<<dim3(NO / 64), dim3(256), 0, stream>>>(w, sbv);
    snn_wslice<<<dim3(NO / 64, NI / 64), dim3(256), 0, stream>>>(w, sbv, wp);

    for (int t0 = 0; t0 < NT; t0 += tca) {
        const int len = (NT - t0 < tca) ? (NT - t0) : tca;
        const int ntiles = (len + BT - 1) / BT;
        snn_xscale<<<dim3(ntiles, NB), dim3(256), 0, stream>>>(x, sa, t0, tca);
        snn_xslice<<<dim3(ntiles, NB, 4), dim3(256), 0, stream>>>(x, sa, xpl, t0, tca, ntiles);
        snn_gemm_i8<<<dim3(NO / BO, ntiles, NB), dim3(256), 0, stream>>>(
            xpl, wp, sa, sbv, cur, t0, tca, ntiles);
        snn_scan_f64<<<dim3((NB * NO) / 64), dim3(64), 0, stream>>>(
            cur, out, vstate, t0, len);
    }
}

// Round 6
// 1060.650 us; speedup vs baseline: 1.5219x; 1.1397x over previous
//
#include <hip/hip_runtime.h>

// SNN layer, round 13: 15-pair Ozaki int8 GEMM (drop weight-class c=5).
//
//  r12 measured: occupancy 23->31% lifted MfmaUtil 41->47.5% (344us). Util
//  tracks waves/CU; next step blocked by acc=96 AGPRs (3 waves/SIMD) AND
//  LDS 48KB (3 blocks). Numerics audit: dropping all slice-pairs with
//  i+j=5 costs ~2.7e-5 abs current error (dropped pairs 1.6e-5 + now-unused
//  slice-5 residuals 2x1.6e-5), inside the 3e-5 spike-decision budget
//  (E[flips] ~ 2e-3; 21-pair scheme measured absmax=0 at 4e-6).
//  Cascade: acc 80 regs (<=128 unified -> 4 waves/SIMD), LDS slot 20KB
//  (2 slots = 40KB -> 4 blocks/CU = 16 waves/CU), MFMA x15/21, DMA x5/6.
//
//  Schedule unchanged from r12 (proven race-free 1-barrier loop):
//    B(kb); STAGE(kb+1 -> slot^1); KITER(slot kb); vmcnt(0); lgkm(0); B(kb+1)
//  Staging: 20 x 1KB chunks/kb; waves 0-1 stage A, waves 2-3 stage B.
//
//  ws: vstate 256KB | SB 8KB | wp 5.2MB | SA | xp (tiled) | cur (tca=512: 219MB)

#define NB 32
#define NI 1024
#define NO 1024
#define NT 1000
#define NS 5          // slices per operand (7 bits each, base 128)
#define BT 64         // t rows per block tile
#define BO 64         // o cols per block tile
#define KI 32         // k per pipeline stage
#define NKB (NI/KI)   // 32 k-blocks
#define TILEB (NS*2*64*16)   // 10240 B per (kb, matrix): [s][kc][row][16]

typedef int i32x4  __attribute__((ext_vector_type(4)));
typedef int i32x16 __attribute__((ext_vector_type(16)));

typedef const __attribute__((address_space(1))) void GVOID;
typedef __attribute__((address_space(3))) void LVOID;
#define GLDS16(g, l) __builtin_amdgcn_global_load_lds((GVOID*)(g), (LVOID*)(l), 16, 0, 0)

// ---- per-o column scale of w: SB = 2^(e+1) > colmax, plus 1/SB ----
__global__ void snn_wscale(const float* __restrict__ w, float* __restrict__ sb)
{
    __shared__ float red[4][64];
    const int tid = threadIdx.x;
    const int ol = tid & 63, iq = tid >> 6;
    const int o = blockIdx.x * 64 + ol;
    float m = 0.f;
    for (int i = iq; i < NI; i += 4) m = fmaxf(m, fabsf(w[(size_t)i * NO + o]));
    red[iq][ol] = m;
    __syncthreads();
    if (iq == 0) {
        m = fmaxf(fmaxf(red[0][ol], red[1][ol]), fmaxf(red[2][ol], red[3][ol]));
        const int e = (__float_as_uint(m) >> 23) & 255;
        float S = 0.f, Si = 0.f;
        if (e) {
            S  = __uint_as_float((unsigned)(e + 1) << 23);
            Si = __uint_as_float((unsigned)(253 - e) << 23);
        }
        sb[o] = S;
        sb[NO + o] = Si;
    }
}

// ---- slice w into tiled planes wp[otile][kb][s][kc][o][16] (5 slices) ----
__global__ void snn_wslice(const float* __restrict__ w, const float* __restrict__ sb,
                           signed char* __restrict__ wp)
{
    __shared__ int sldw[NS][64][16];   // XOR-swizzled dword cols
    const int tid = threadIdx.x;
    const int ol = tid & 63, iq = tid >> 6;
    const int o0 = blockIdx.x * 64, ic = blockIdx.y * 64;
    const float inv = sb[NO + o0 + ol];
#pragma unroll
    for (int q4 = 0; q4 < 16; q4 += 4) {
        int pk[NS] = {0, 0, 0, 0, 0};
#pragma unroll
        for (int j = 0; j < 4; ++j) {
            const int i = ic + iq * 16 + q4 + j;
            float wv = w[(size_t)i * NO + o0 + ol] * inv;   // exact (pow2 scale)
#pragma unroll
            for (int s = 0; s < NS; ++s) {
                const float f = wv * 128.f;     // exact, |f|<128
                const int a = (int)f;           // trunc in [-127,127]
                wv = f - (float)a;              // exact remainder
                pk[s] |= (a & 255) << (8 * j);
            }
        }
        const int cdw = (iq * 16 + q4) >> 2;
#pragma unroll
        for (int s = 0; s < NS; ++s) sldw[s][ol][cdw ^ (ol & 15)] = pk[s];
    }
    __syncthreads();
    // 5120 dwords out: [kbi(2)][s(5)][kc(2)][row(64)][d4(4)], contiguous per kbi
    signed char* tb = wp + (size_t)blockIdx.x * (NKB * TILEB) + (size_t)(ic >> 5) * TILEB;
#pragma unroll
    for (int p = 0; p < 20; ++p) {
        const int idx = p * 256 + tid;
        const int kbi = idx >= 2560;
        const int ld  = idx - (kbi ? 2560 : 0);
        const int s  = ld >> 9;
        const int kc = (ld >> 8) & 1;
        const int r  = (ld >> 2) & 63;
        const int d4 = ld & 3;
        *(int*)&tb[(size_t)kbi * TILEB + (size_t)ld * 4] =
            sldw[s][r][(kbi * 8 + kc * 4 + d4) ^ (r & 15)];
    }
}

// ---- per-(b,t) scale SA = 2^(e+1) > rowmax ----
__global__ void snn_xscale(const float* __restrict__ x, float* __restrict__ sa,
                           int t0, int tca)
{
    __shared__ float red[4][64];
    const int tid = threadIdx.x;
    const int tl = tid & 63, iq = tid >> 6;
    const int b = blockIdx.y;
    const int tt = blockIdx.x * 64;
    const int tg = t0 + tt + tl;
    const float* xb = x + (size_t)b * NI * NT;
    float m = 0.f;
    if (tg < NT)
        for (int i = iq; i < NI; i += 4) m = fmaxf(m, fabsf(xb[(size_t)i * NT + tg]));
    red[iq][tl] = m;
    __syncthreads();
    if (iq == 0) {
        m = fmaxf(fmaxf(red[0][tl], red[1][tl]), fmaxf(red[2][tl], red[3][tl]));
        const int e = (__float_as_uint(m) >> 23) & 255;
        sa[(size_t)b * tca + tt + tl] = e ? __uint_as_float((unsigned)(e + 1) << 23) : 0.f;
    }
}

// ---- slice x into tiled planes xp[b][tile][kb][s][kc][t][16] (5 slices) ----
__global__ void snn_xslice(const float* __restrict__ x, const float* __restrict__ sa,
                           signed char* __restrict__ xp, int t0, int tca, int ntiles)
{
    __shared__ int sldw[NS][64][16];
    const int tid = threadIdx.x;
    const int tl = tid & 63, iq = tid >> 6;
    const int b = blockIdx.y;
    const int tile = blockIdx.x;
    const int tg = t0 + tile * 64 + tl;
    const bool valid = (tg < NT);
    const float* xb = x + (size_t)b * NI * NT;
    const float S = sa[(size_t)b * tca + tile * 64 + tl];
    const float inv = (S > 0.f)
        ? __uint_as_float((254u - (__float_as_uint(S) >> 23)) << 23) : 0.f;  // exact 1/S
    signed char* tb = xp + (size_t)(b * ntiles + tile) * (NKB * TILEB);

    for (int c4 = 0; c4 < 4; ++c4) {
        const int ic = blockIdx.z * 256 + c4 * 64;
#pragma unroll
        for (int q4 = 0; q4 < 16; q4 += 4) {
            int pk[NS] = {0, 0, 0, 0, 0};
#pragma unroll
            for (int j = 0; j < 4; ++j) {
                const int i = ic + iq * 16 + q4 + j;
                float wv = valid ? xb[(size_t)i * NT + tg] * inv : 0.f;
#pragma unroll
                for (int s = 0; s < NS; ++s) {
                    const float f = wv * 128.f;
                    const int a = (int)f;
                    wv = f - (float)a;
                    pk[s] |= (a & 255) << (8 * j);
                }
            }
            const int cdw = (iq * 16 + q4) >> 2;
#pragma unroll
            for (int s = 0; s < NS; ++s) sldw[s][tl][cdw ^ (tl & 15)] = pk[s];
        }
        __syncthreads();
        signed char* kbb = tb + (size_t)(ic >> 5) * TILEB;
#pragma unroll
        for (int p = 0; p < 20; ++p) {
            const int idx = p * 256 + tid;
            const int kbi = idx >= 2560;
            const int ld  = idx - (kbi ? 2560 : 0);
            const int s  = ld >> 9;
            const int kc = (ld >> 8) & 1;
            const int r  = (ld >> 2) & 63;
            const int d4 = ld & 3;
            *(int*)&kbb[(size_t)kbi * TILEB + (size_t)ld * 4] =
                sldw[s][r][(kbi * 8 + kc * 4 + d4) ^ (r & 15)];
        }
        __syncthreads();
    }
}

// ---- pipelined int8 MFMA GEMM: 64x64 block, 4 waves of 32x32 ----
// 2-slot LDS double buffer (40KB -> 4 blocks/CU), 15 slice pairs (c<=4),
// 5 weight-grouped accumulators (80 regs -> 4 waves/SIMD), 1 barrier/k-iter.
__global__ __launch_bounds__(256, 4)
void snn_gemm_i8(const signed char* __restrict__ xp, const signed char* __restrict__ wp,
                 const float* __restrict__ sa, const float* __restrict__ sb,
                 double* __restrict__ cur, int t0, int tca, int ntiles)
{
    __shared__ signed char As[2][TILEB];   // 20 KB
    __shared__ signed char Bs[2][TILEB];   // 20 KB

    const int tid  = threadIdx.x;
    const int lane = tid & 63;
    const int wave = tid >> 6;
    const int wm = (wave >> 1) * 32;
    const int wn = (wave & 1) * 32;
    const int l31 = lane & 31;
    const int hi  = lane >> 5;

    // bijective XCD-aware remap (m204); nwg = 512*ntiles, always % 8 == 0
    int lid = blockIdx.x + (int)gridDim.x * (blockIdx.y + (int)gridDim.y * blockIdx.z);
    {
        const int nwg = (int)(gridDim.x * gridDim.y * gridDim.z);
        const int q = nwg >> 3, r = nwg & 7;
        const int xcd = lid & 7, off = lid >> 3;
        lid = (xcd < r ? xcd * (q + 1) : r * (q + 1) + (xcd - r) * q) + off;
    }
    const int ox  = lid & 15;          // o-tile (gridDim.x == 16)
    const int rst = lid >> 4;
    const int ty  = rst % ntiles;      // t-tile
    const int b   = rst / ntiles;      // batch

    const int o0 = ox * BO;
    const int bt = ty * BT;

    i32x16 acc[NS];
#pragma unroll
    for (int c = 0; c < NS; ++c) acc[c] = (i32x16)0;

    // per-lane global bases (chunk offset added per-stage)
    const signed char* AgL = xp + (size_t)(b * ntiles + ty) * (NKB * TILEB) + lane * 16;
    const signed char* BgL = wp + (size_t)ox * (NKB * TILEB) + lane * 16;

    // staging: 20 x 1KB chunks per kb; waves 0-1 -> A (chunks 0..9),
    // waves 2-3 -> B (chunks 0..9). 5 GLDS16 per wave, uniform vmcnt.
#define STAGE(src, bsel) do {                                                  \
    if (wave < 2) {                                                            \
        _Pragma("unroll")                                                      \
        for (int u = 0; u < 5; ++u) {                                          \
            const int ck = wave * 5 + u;                                       \
            GLDS16(AgL + (size_t)(src) * TILEB + ck * 1024,                    \
                   &As[bsel][0] + ck * 1024);                                  \
        }                                                                      \
    } else {                                                                   \
        _Pragma("unroll")                                                      \
        for (int u = 0; u < 5; ++u) {                                          \
            const int ck = (wave - 2) * 5 + u;                                 \
            GLDS16(BgL + (size_t)(src) * TILEB + ck * 1024,                    \
                   &Bs[bsel][0] + ck * 1024);                                  \
        }                                                                      \
    } } while (0)

    const int abase = hi * 1024 + (wm + l31) * 16;   // [kc=hi][row][16]
    const int bbase = hi * 1024 + (wn + l31) * 16;

    // one k-iteration: 5 B frags + rolling A frags, 15 MFMAs (c = i+j <= 4)
#define KITER(slot) do {                                                       \
    const signed char* Ab_ = &As[slot][0];                                     \
    const signed char* Bb_ = &Bs[slot][0];                                     \
    i32x4 bf[NS];                                                              \
    _Pragma("unroll")                                                          \
    for (int s = 0; s < NS; ++s) bf[s] = *(const i32x4*)&Bb_[bbase + s * 2048];\
    i32x4 a0 = *(const i32x4*)&Ab_[abase];                                     \
    _Pragma("unroll")                                                          \
    for (int i = 0; i < NS; ++i) {                                             \
        i32x4 a1 = a0;                                                         \
        if (i + 1 < NS) a1 = *(const i32x4*)&Ab_[abase + (i + 1) * 2048];      \
        __builtin_amdgcn_s_setprio(1);                                         \
        _Pragma("unroll")                                                      \
        for (int c = NS - 1; c >= i; --c)                                      \
            acc[c] = __builtin_amdgcn_mfma_i32_32x32x32_i8(a0, bf[c - i],      \
                                                           acc[c], 0, 0, 0);   \
        __builtin_amdgcn_s_setprio(0);                                         \
        a0 = a1;                                                               \
    } } while (0)

    // prologue: DMA(0) complete everywhere before first reads
    STAGE(0, 0);
    asm volatile("s_waitcnt vmcnt(0)" ::: "memory");
    __builtin_amdgcn_s_barrier();

    for (int kb = 0; kb < NKB - 1; ++kb) {
        // post-B(kb): all waves' reads of slot[(kb+1)&1] (iter kb-1) drained
        STAGE(kb + 1, (kb + 1) & 1);
        KITER(kb & 1);
        // DMA(kb+1) complete + own ds_reads drained before B(kb+1)
        asm volatile("s_waitcnt vmcnt(0)" ::: "memory");
        asm volatile("s_waitcnt lgkmcnt(0)" ::: "memory");
        __builtin_amdgcn_sched_barrier(0);
        __builtin_amdgcn_s_barrier();
    }
    KITER((NKB - 1) & 1);   // last k-block: nothing to stage
#undef STAGE
#undef KITER

    // Probe D reg->row mapping (epilogue: keeps 16 regs out of the main loop).
    // A=I(32x32), B[k][n]=k => D[m][n]=m (col is lane&31).
    int prow[16];
    {
        i32x4 pa, pb;
#pragma unroll
        for (int q = 0; q < 4; ++q) {
            int va = 0, vb = 0;
#pragma unroll
            for (int jj = 0; jj < 4; ++jj) {
                const int k = 16 * hi + q * 4 + jj;
                if (l31 == k) va |= 1 << (8 * jj);
                vb |= (k & 255) << (8 * jj);
            }
            pa[q] = va; pb[q] = vb;
        }
        i32x16 pp = (i32x16)0;
        pp = __builtin_amdgcn_mfma_i32_32x32x32_i8(pa, pb, pp, 0, 0, 0);
#pragma unroll
        for (int r = 0; r < 16; ++r) prow[r] = pp[r] & 31;
    }

    // epilogue: exact i32 partials -> fp64 currents (weights 128^-(c+2))
    const double c128[NS] = {0x1p-14, 0x1p-21, 0x1p-28, 0x1p-35, 0x1p-42};
    const int ocol = o0 + wn + l31;
    const double sbv = (double)sb[ocol];
#pragma unroll
    for (int r = 0; r < 16; ++r) {
        const int trow = bt + wm + prow[r];
        double v = 0.0;
#pragma unroll
        for (int c = 0; c < NS; ++c) v += (double)acc[c][r] * c128[c];
        v *= (double)sa[(size_t)b * tca + trow] * sbv;
        if (t0 + trow < NT)
            cur[((size_t)trow * NB + b) * NO + ocol] = v;
    }
}

// LIF scan: one thread per (b,o); cur chunk is [tc][b*NO+o] fp64. 32-step
// double buffer; 128B contiguous stores per thread per iter. (Unchanged, proven.)
#define NC 32
__global__ __launch_bounds__(64)
void snn_scan_f64(const double* __restrict__ cur, float* __restrict__ out,
                  double* __restrict__ vstate, int t0, int len)
{
    const int gid = blockIdx.x * 64 + threadIdx.x;   // b*NO + o
    const double dt = 0.001 / 50.0;                  // MS / TAU, IEEE double

    double v = (t0 == 0) ? 0.0 : vstate[gid];
    const double* cp = cur + gid;                    // stride NB*NO per t-step
    float* op = out + (size_t)gid * NT + t0;         // thread-contiguous in t

    const size_t ts = (size_t)NB * NO;               // 32768
    const int nb = len / NC;                         // full 32-blocks
    const int rem = len - nb * NC;                   // tail (multiple of 8)

    double A[NC], B[NC];
#pragma unroll
    for (int j = 0; j < NC; ++j) A[j] = (j < len) ? cp[(size_t)j * ts] : 0.0;

    for (int blk = 0; blk < nb; ++blk) {
        const int next = (blk + 1) * NC;
#pragma unroll
        for (int j = 0; j < NC; ++j)
            B[j] = (next + j < len) ? cp[(size_t)(next + j) * ts] : 0.0;

#pragma unroll
        for (int q = 0; q < NC; q += 8) {
            float s[8];
#pragma unroll
            for (int j = 0; j < 8; ++j) {
                v = v + (A[q + j] - v) * dt;
                const bool sp = (v >= 1.0);
                s[j] = sp ? 1.0f : 0.0f;
                if (sp) v = 0.0;
            }
            *(float4*)(op + q)     = make_float4(s[0], s[1], s[2], s[3]);
            *(float4*)(op + q + 4) = make_float4(s[4], s[5], s[6], s[7]);
        }
        op += NC;
#pragma unroll
        for (int j = 0; j < NC; ++j) A[j] = B[j];
    }

    for (int q = 0; q < rem; q += 8) {               // tail (data already in A)
        float s[8];
#pragma unroll
        for (int j = 0; j < 8; ++j) {
            v = v + (A[q + j] - v) * dt;
            const bool sp = (v >= 1.0);
            s[j] = sp ? 1.0f : 0.0f;
            if (sp) v = 0.0;
        }
        *(float4*)(op + q)     = make_float4(s[0], s[1], s[2], s[3]);
        *(float4*)(op + q + 4) = make_float4(s[4], s[5], s[6], s[7]);
    }
    vstate[gid] = v;
}

extern "C" void kernel_launch(void* const* d_in, const int* in_sizes, int n_in,
                              void* d_out, int out_size, void* d_ws, size_t ws_size,
                              hipStream_t stream)
{
    const float* x = (const float*)d_in[0];
    const float* w = (const float*)d_in[1];
    float* out = (float*)d_out;

    char* p = (char*)d_ws;
    double* vstate = (double*)p;         p += (size_t)NB * NO * 8;       // 256KB
    float* sbv = (float*)p;              p += (size_t)2 * NO * 4;        // 8KB
    signed char* wp = (signed char*)p;   p += (size_t)(NO / 64) * NKB * TILEB;  // 5.2MB

    const size_t fixed = (size_t)(p - (char*)d_ws);
    const size_t per_t = (size_t)NB * 4                // SA
                       + (size_t)NS * NB * NI          // x slices (tiled)
                       + (size_t)NB * NO * 8;          // cur
    int tca = 512;                                     // t-chunk, multiple of 64
    while (tca > 64 && fixed + (size_t)tca * per_t > ws_size) tca -= 64;

    float* sa = (float*)p;               p += (size_t)NB * tca * 4;
    signed char* xpl = (signed char*)p;  p += (size_t)NB * (tca / 64) * NKB * TILEB;
    double* cur = (double*)p;

    snn_wscale<<<dim3(NO / 64), dim3(256), 0, stream>>>(w, sbv);
    snn_wslice<<<dim3(NO / 64, NI / 64), dim3(256), 0, stream>>>(w, sbv, wp);

    for (int t0 = 0; t0 < NT; t0 += tca) {
        const int len = (NT - t0 < tca) ? (NT - t0) : tca;
        const int ntiles = (len + BT - 1) / BT;
        snn_xscale<<<dim3(ntiles, NB), dim3(256), 0, stream>>>(x, sa, t0, tca);
        snn_xslice<<<dim3(ntiles, NB, 4), dim3(256), 0, stream>>>(x, sa, xpl, t0, tca, ntiles);
        snn_gemm_i8<<<dim3(NO / BO, ntiles, NB), dim3(256), 0, stream>>>(
            xpl, wp, sa, sbv, cur, t0, tca, ntiles);
        snn_scan_f64<<<dim3((NB * NO) / 64), dim3(64), 0, stream>>>(
            cur, out, vstate, t0, len);
    }
}